// Round 12
// baseline (280.793 us; speedup 1.0000x reference)
//
#include <hip/hip_runtime.h>

typedef __bf16 bf16;
typedef __bf16 bf16x4 __attribute__((ext_vector_type(4)));
typedef __bf16 bf16x8 __attribute__((ext_vector_type(8)));
typedef float f32x4 __attribute__((ext_vector_type(4)));

#define D_MODEL 1024
#define PROJ    256
#define SEQ     2048
#define BATCH   2
#define TOK     4096   // BATCH*SEQ
#define NH      16
#define DH      64
#define NEG_BIG (-1e30f)
#define QSCALE  0.18033688011112042f   // 0.125 * log2(e), folded into Qh

#if __has_builtin(__builtin_amdgcn_exp2f)
#define EXP2(x) __builtin_amdgcn_exp2f(x)
#else
#define EXP2(x) exp2f(x)
#endif

typedef __attribute__((address_space(3))) unsigned int  lds_u32;
typedef __attribute__((address_space(1))) unsigned int  glb_u32;

// async 16B/lane global->LDS (gfx950 global_load_lds_dwordx4).
__device__ __forceinline__ void gl2lds16(const void* gsrc, void* ldst) {
    __builtin_amdgcn_global_load_lds((const glb_u32*)gsrc, (lds_u32*)ldst, 16, 0, 0);
}

// ---------------------------------------------------------------------------
// DPP 16-lane row sum (groups are contiguous 16-lane DPP rows).
template <int CTRL>
__device__ __forceinline__ float dppmov(float x) {
    int i = __builtin_bit_cast(int, x);
    i = __builtin_amdgcn_update_dpp(i, i, CTRL, 0xf, 0xf, false);
    return __builtin_bit_cast(float, i);
}
__device__ __forceinline__ float rowsum16(float v) {
    v += dppmov<0xB1>(v);
    v += dppmov<0x4E>(v);
    v += dppmov<0x141>(v);
    v += dppmov<0x140>(v);
    return v;
}

// ---------------------------------------------------------------------------
// One kernel for all weight prep: W_o cvt + 4 transposes (fp32 -> bf16 n-major).
__global__ void prep_weights_kernel(
    const float* __restrict__ W_o,  const float* __restrict__ W_dq,
    const float* __restrict__ W_dkv, const float* __restrict__ W_uq,
    const float* __restrict__ W_ukv,
    bf16* __restrict__ Wo16, bf16* __restrict__ Wt_dq, bf16* __restrict__ Wt_dkv,
    bf16* __restrict__ Wt_uq, bf16* __restrict__ Wt_ukv) {
    const int R0 = 1048576;
    const int R1 = R0 + 262144;
    const int R2 = R1 + 262144;
    const int R3 = R2 + 262144;
    const int R4 = R3 + 524288;
    for (int i = blockIdx.x * blockDim.x + threadIdx.x; i < R4;
         i += gridDim.x * blockDim.x) {
        if (i < R0) {
            Wo16[i] = (bf16)W_o[i];
        } else if (i < R1) {
            int j = i - R0, n = j >> 10, k = j & 1023;
            Wt_dq[j] = (bf16)W_dq[k * 256 + n];
        } else if (i < R2) {
            int j = i - R1, n = j >> 10, k = j & 1023;
            Wt_dkv[j] = (bf16)W_dkv[k * 256 + n];
        } else if (i < R3) {
            int j = i - R2, n = j >> 8, k = j & 255;
            Wt_uq[j] = (bf16)W_uq[k * 1024 + n];
        } else {
            int j = i - R3, n = j >> 8, k = j & 255;
            Wt_ukv[j] = (bf16)W_ukv[k * 2048 + n];
        }
    }
}

// ---------------------------------------------------------------------------
// Dual LN-GEMM: blockIdx.y=0 -> cq=LN(x@W_dq), =1 -> ckv=LN(x@W_dkv).
__global__ __launch_bounds__(256) void gemm_ln_kernel(
    const float* __restrict__ x,
    const bf16* __restrict__ Wt_q, const bf16* __restrict__ Wt_kv,
    const float* __restrict__ q_g, const float* __restrict__ q_b,
    const float* __restrict__ kv_g, const float* __restrict__ kv_b,
    bf16* __restrict__ cq, bf16* __restrict__ ckv) {
    const int K = 1024;
    const bf16* Wt = blockIdx.y ? Wt_kv : Wt_q;
    const float* gamma = blockIdx.y ? kv_g : q_g;
    const float* beta  = blockIdx.y ? kv_b : q_b;
    bf16* out = blockIdx.y ? ckv : cq;

    const int m0 = blockIdx.x * 16;
    const int wv = threadIdx.x >> 6;
    const int lane = threadIdx.x & 63;
    const int g = lane >> 4;
    const int ln16 = lane & 15;
    const int ncol0 = wv * 64;

    f32x4 acc[4] = {};
    const float* arow = x + (size_t)(m0 + ln16) * K + g * 8;
    for (int k0 = 0; k0 < K; k0 += 32) {
        f32x4 f0 = *(const f32x4*)(arow + k0);
        f32x4 f1 = *(const f32x4*)(arow + k0 + 4);
        bf16x8 a;
#pragma unroll
        for (int j = 0; j < 4; ++j) { a[j] = (bf16)f0[j]; a[4 + j] = (bf16)f1[j]; }
#pragma unroll
        for (int t = 0; t < 4; ++t) {
            const bf16* bp = Wt + (size_t)(ncol0 + 16 * t + ln16) * K + k0 + g * 8;
            bf16x8 b = *(const bf16x8*)bp;
            acc[t] = __builtin_amdgcn_mfma_f32_16x16x32_bf16(a, b, acc[t], 0, 0, 0);
        }
    }

    float s1[4], s2[4];
#pragma unroll
    for (int r = 0; r < 4; ++r) {
        float a = 0.f, b = 0.f;
#pragma unroll
        for (int t = 0; t < 4; ++t) { float v = acc[t][r]; a += v; b += v * v; }
        s1[r] = rowsum16(a); s2[r] = rowsum16(b);
    }
    __shared__ float red1[4][16];
    __shared__ float red2[4][16];
    if (ln16 == 0) {
#pragma unroll
        for (int r = 0; r < 4; ++r) {
            red1[wv][g * 4 + r] = s1[r];
            red2[wv][g * 4 + r] = s2[r];
        }
    }
    __syncthreads();
#pragma unroll
    for (int r = 0; r < 4; ++r) {
        int row = g * 4 + r;
        float t1 = red1[0][row] + red1[1][row] + red1[2][row] + red1[3][row];
        float t2 = red2[0][row] + red2[1][row] + red2[2][row] + red2[3][row];
        float mu = t1 * (1.0f / 256.0f);
        float var = t2 * (1.0f / 256.0f) - mu * mu;
        float rs = rsqrtf(var + 1e-5f);
#pragma unroll
        for (int t = 0; t < 4; ++t) {
            int col = ncol0 + 16 * t + ln16;
            float v = (acc[t][r] - mu) * rs * gamma[col] + beta[col];
            out[(size_t)(m0 + row) * PROJ + col] = (bf16)v;
        }
    }
}

// ---------------------------------------------------------------------------
// m97-style LDS-staged MFMA GEMM. BM=64, BN=128, BK=32, 4 waves/block.
template <int MODE, typename OutT>
__global__ __launch_bounds__(256) void gemm_lds_kernel(
    const bf16* __restrict__ A, const bf16* __restrict__ Bt,
    OutT* __restrict__ C, bf16* __restrict__ C2, int M, int N, int K) {
    __shared__ alignas(16) bf16 tA[64 * 32];
    __shared__ alignas(16) bf16 tB[128 * 32];

    const int w = threadIdx.x >> 6;
    const int lane = threadIdx.x & 63;
    const int g = lane >> 4;
    const int ln16 = lane & 15;
    const int wr = w >> 1;
    const int wc = w & 1;

    const int m0 = blockIdx.x * 64;
    const int n0 = blockIdx.y * 128;

    const int crow = lane >> 2;
    const int ckc = lane & 3;
    const bf16* gA  = A  + (size_t)(m0 + w * 16 + crow) * K + ckc * 8;
    const bf16* gB0 = Bt + (size_t)(n0 + w * 16 + crow) * K + ckc * 8;
    const bf16* gB1 = Bt + (size_t)(n0 + 64 + w * 16 + crow) * K + ckc * 8;
    char* lA  = (char*)tA + w * 1024;
    char* lB0 = (char*)tB + w * 1024;
    char* lB1 = (char*)tB + 4096 + w * 1024;

    f32x4 acc[2][4] = {};
    for (int k0 = 0; k0 < K; k0 += 32) {
        gl2lds16(gA + k0, lA);
        gl2lds16(gB0 + k0, lB0);
        gl2lds16(gB1 + k0, lB1);
        __syncthreads();

        bf16x8 af[2], bf[4];
#pragma unroll
        for (int s = 0; s < 2; ++s)
            af[s] = *(const bf16x8*)(tA + (wr * 32 + s * 16 + ln16) * 32 + g * 8);
#pragma unroll
        for (int t = 0; t < 4; ++t)
            bf[t] = *(const bf16x8*)(tB + (wc * 64 + t * 16 + ln16) * 32 + g * 8);
#pragma unroll
        for (int s = 0; s < 2; ++s)
#pragma unroll
            for (int t = 0; t < 4; ++t)
                acc[s][t] = __builtin_amdgcn_mfma_f32_16x16x32_bf16(
                    af[s], bf[t], acc[s][t], 0, 0, 0);
        __syncthreads();
    }

#pragma unroll
    for (int s = 0; s < 2; ++s)
#pragma unroll
        for (int t = 0; t < 4; ++t) {
            const int col = n0 + wc * 64 + t * 16 + ln16;
            const int tok0 = m0 + wr * 32 + s * 16 + g * 4;
            if (MODE == 2 && col >= 1024) {
                int cc = col - 1024;
                int h = cc >> 6, d = cc & 63;
                int b = tok0 >> 11, sq = tok0 & 2047;
                bf16x4 pk;
#pragma unroll
                for (int r = 0; r < 4; ++r) pk[r] = (bf16)acc[s][t][r];
                *(bf16x4*)(C2 + ((size_t)((b * 16 + h) * 64 + d) * SEQ + sq)) = pk;
            } else {
#pragma unroll
                for (int r = 0; r < 4; ++r) {
                    int row = tok0 + r;
                    float v = acc[s][t][r];
                    if (MODE == 0) {
                        C[(size_t)row * N + col] = (OutT)v;
                    } else {
                        if (MODE == 1) v *= QSCALE;
                        int h = col >> 6, d = col & 63;
                        int b = row >> 11, sq = row & 2047;
                        C[((size_t)((b * 16 + h) * 2048 + sq)) * 64 + d] = (OutT)v;
                    }
                }
            }
        }
}

// ---------------------------------------------------------------------------
// Split-K paired flash attention, LDS-free (S^T = K·Q^T formulation),
// 2-tile unrolled k-loop with all loads issued up front (no prefetch copies,
// no per-iteration vmcnt(0) drain).
__device__ __forceinline__ void load_kfrags(const bf16* __restrict__ Kbh, int k0,
                                            int g, int ln16, bf16x8* Kf) {
    const int base = ((ln16 & 12) << 1) + (ln16 & 3);   // 8*(ln16>>2)+(ln16&3)
#pragma unroll
    for (int c = 0; c < 4; ++c) {
        const int row = k0 + base + (c & 1) * 4 + ((c >> 1) << 5);
        const bf16* kp = Kbh + (size_t)row * DH + g * 8;
        Kf[2 * c]     = *(const bf16x8*)kp;
        Kf[2 * c + 1] = *(const bf16x8*)(kp + 32);
    }
}
__device__ __forceinline__ void load_vfrags(const bf16* __restrict__ Vbh, int k0,
                                            int g, int ln16, bf16x8* Vf) {
#pragma unroll
    for (int t = 0; t < 4; ++t) {
        const bf16* vp = Vbh + (size_t)(16 * t + ln16) * SEQ + k0 + g * 8;
        Vf[2 * t]     = *(const bf16x8*)vp;
        Vf[2 * t + 1] = *(const bf16x8*)(vp + 32);
    }
}

__device__ __forceinline__ void qk_exp_pack(
    int k0, int q, bool masked, int g, int ln16,
    bf16x8 aq0, bf16x8 aq1, const bf16x8* Kf,
    float& li, bf16x8& P1, bf16x8& P2) {
    f32x4 sc[4];
#pragma unroll
    for (int c = 0; c < 4; ++c) {
        f32x4 z = {};
        z = __builtin_amdgcn_mfma_f32_16x16x32_bf16(Kf[2 * c], aq0, z, 0, 0, 0);
        z = __builtin_amdgcn_mfma_f32_16x16x32_bf16(Kf[2 * c + 1], aq1, z, 0, 0, 0);
        sc[c] = z;
    }
    if (masked) {
        const int kb = k0 + 8 * g;
#pragma unroll
        for (int c = 0; c < 4; ++c)
#pragma unroll
            for (int r = 0; r < 4; ++r) {
                int kcol = kb + (c & 1) * 4 + r + ((c >> 1) << 5);
                if (kcol > q) sc[c][r] = NEG_BIG;
            }
    }
#pragma unroll
    for (int c = 0; c < 4; ++c)
#pragma unroll
        for (int r = 0; r < 4; ++r) {
            float p = EXP2(sc[c][r]);
            sc[c][r] = p;
            li += p;
        }
#pragma unroll
    for (int r = 0; r < 4; ++r) {
        P1[r] = (bf16)sc[0][r]; P1[4 + r] = (bf16)sc[1][r];
        P2[r] = (bf16)sc[2][r]; P2[4 + r] = (bf16)sc[3][r];
    }
}

__device__ __forceinline__ void pv_accum(
    bf16x8 P1, bf16x8 P2, const bf16x8* Vf, f32x4* o) {
#pragma unroll
    for (int t = 0; t < 4; ++t) {
        o[t] = __builtin_amdgcn_mfma_f32_16x16x32_bf16(Vf[2 * t], P1, o[t], 0, 0, 0);
        o[t] = __builtin_amdgcn_mfma_f32_16x16x32_bf16(Vf[2 * t + 1], P2, o[t], 0, 0, 0);
    }
}

// process one k-tile (both chains) given already-loaded fragments
__device__ __forceinline__ void do_tile(
    int kt, int lastL, int lastH, int qL, int qH, int g, int ln16,
    bf16x8 aqL0, bf16x8 aqL1, bf16x8 aqH0, bf16x8 aqH1,
    const bf16x8* Kf, const bf16x8* Vf,
    float& liL, float& liH, f32x4* oL, f32x4* oH) {
    const int k0 = kt * 64;
    const bool actL = (kt <= lastL);
    bf16x8 P1L, P2L, P1H, P2H;
    if (actL) qk_exp_pack(k0, qL, kt == lastL, g, ln16, aqL0, aqL1, Kf, liL, P1L, P2L);
    qk_exp_pack(k0, qH, kt == lastH, g, ln16, aqH0, aqH1, Kf, liH, P1H, P2H);
    if (actL) pv_accum(P1L, P2L, Vf, oL);
    pv_accum(P1H, P2H, Vf, oH);
}

// (256,2): (256,4) clamps to 64 VGPR and spills (round-7 evidence).
__global__ __launch_bounds__(256, 2) void attn_kernel(
    const bf16* __restrict__ Qh, const bf16* __restrict__ Kh,
    const bf16* __restrict__ Vt,
    float* __restrict__ Opart, float* __restrict__ lpart) {
    const int lane = threadIdx.x & 63;
    const int g = lane >> 4;
    const int ln16 = lane & 15;
    const int wv = threadIdx.x >> 6;

    const int bh   = blockIdx.x & 31;
    const int gidx = blockIdx.x >> 5;          // 0..31
    const int p    = gidx * 2 + (wv >> 1);     // 0..63
    const int sp   = wv & 1;                   // kt parity
    const int pid  = (p << 5) | bh;            // matches combine indexing

    const int qbL = p * 16;
    const int qbH = (127 - p) * 16;
    const int lastL = p >> 2;
    const int lastH = (127 - p) >> 2;

    const bf16* Kbh = Kh + (size_t)bh * SEQ * DH;
    const bf16* Vbh = Vt + (size_t)bh * DH * SEQ;

    const bf16* qpL = Qh + ((size_t)bh * SEQ + qbL + ln16) * DH + g * 8;
    const bf16* qpH = Qh + ((size_t)bh * SEQ + qbH + ln16) * DH + g * 8;
    bf16x8 aqL0 = *(const bf16x8*)qpL, aqL1 = *(const bf16x8*)(qpL + 32);
    bf16x8 aqH0 = *(const bf16x8*)qpH, aqH1 = *(const bf16x8*)(qpH + 32);

    const int qL = qbL + ln16;
    const int qH = qbH + ln16;

    f32x4 oL[4] = {}, oH[4] = {};
    float liL = 0.f, liH = 0.f;

    bf16x8 Ka[8], Kb[8], Va[8], Vb[8];

    int kt = sp;
    // 2-tile bodies: all 32 loads issued before any use; compiler can emit
    // graded vmcnt waits (24/16/8/0) since loads are ordered by first use.
    for (; kt + 2 <= lastH; kt += 4) {
        load_kfrags(Kbh, kt * 64, g, ln16, Ka);
        load_vfrags(Vbh, kt * 64, g, ln16, Va);
        load_kfrags(Kbh, (kt + 2) * 64, g, ln16, Kb);
        load_vfrags(Vbh, (kt + 2) * 64, g, ln16, Vb);
        do_tile(kt, lastL, lastH, qL, qH, g, ln16,
                aqL0, aqL1, aqH0, aqH1, Ka, Va, liL, liH, oL, oH);
        do_tile(kt + 2, lastL, lastH, qL, qH, g, ln16,
                aqL0, aqL1, aqH0, aqH1, Kb, Vb, liL, liH, oL, oH);
    }
    if (kt <= lastH) {   // odd-count tail tile
        load_kfrags(Kbh, kt * 64, g, ln16, Ka);
        load_vfrags(Vbh, kt * 64, g, ln16, Va);
        do_tile(kt, lastL, lastH, qL, qH, g, ln16,
                aqL0, aqL1, aqH0, aqH1, Ka, Va, liL, liH, oL, oH);
    }

    liL += __shfl_xor(liL, 16); liL += __shfl_xor(liL, 32);
    liH += __shfl_xor(liH, 16); liH += __shfl_xor(liH, 32);

    const int slotL = (pid * 2 + sp) * 2;
    const int slotH = slotL + 1;
    float* OL = Opart + (size_t)slotL * 1024;
    float* OH = Opart + (size_t)slotH * 1024;
#pragma unroll
    for (int t = 0; t < 4; ++t) {
        *(f32x4*)(OL + ln16 * 64 + 16 * t + 4 * g) = oL[t];
        *(f32x4*)(OH + ln16 * 64 + 16 * t + 4 * g) = oH[t];
    }
    if (lane < 16) {
        lpart[slotL * 16 + ln16] = liL;
        lpart[slotH * 16 + ln16] = liH;
    }
}

// ---------------------------------------------------------------------------
// Combine: sum the two parity partials, normalize, write AT token-major.
__global__ __launch_bounds__(256) void combine_kernel(
    const float* __restrict__ Opart, const float* __restrict__ lpart,
    bf16* __restrict__ AT) {
    int idx = blockIdx.x * 256 + threadIdx.x;      // 32*2048*64 = 4.19M
    int d = idx & 63;
    int s = (idx >> 6) & 2047;
    int bh = idx >> 17;
    int qt = s >> 4, row = s & 15;
    int which = (qt >= 64) ? 1 : 0;
    int p = which ? (127 - qt) : qt;
    int pid = p * 32 + bh;
    int s0 = (pid * 2 + 0) * 2 + which;
    int s1 = (pid * 2 + 1) * 2 + which;
    float O = Opart[(size_t)s0 * 1024 + row * 64 + d] +
              Opart[(size_t)s1 * 1024 + row * 64 + d];
    float l = lpart[s0 * 16 + row] + lpart[s1 * 16 + row];
    int token = (bh >> 4) * 2048 + s;
    int col = (bh & 15) * 64 + d;
    AT[(size_t)token * 1024 + col] = (bf16)(O / l);
}

// ---------------------------------------------------------------------------
extern "C" void kernel_launch(void* const* d_in, const int* in_sizes, int n_in,
                              void* d_out, int out_size, void* d_ws, size_t ws_size,
                              hipStream_t stream) {
    const float* x     = (const float*)d_in[0];
    const float* W_dq  = (const float*)d_in[1];
    const float* W_uq  = (const float*)d_in[2];
    const float* q_g   = (const float*)d_in[3];
    const float* q_b   = (const float*)d_in[4];
    const float* W_dkv = (const float*)d_in[5];
    const float* W_ukv = (const float*)d_in[6];
    const float* kv_g  = (const float*)d_in[7];
    const float* kv_b  = (const float*)d_in[8];
    const float* W_o   = (const float*)d_in[9];

    char* ws = (char*)d_ws;
    size_t off = 0;
    bf16* Wo16   = (bf16*)(ws + off); off += (size_t)D_MODEL * D_MODEL * 2;
    bf16* Wt_dq  = (bf16*)(ws + off); off += (size_t)PROJ * D_MODEL * 2;
    bf16* Wt_dkv = (bf16*)(ws + off); off += (size_t)PROJ * D_MODEL * 2;
    bf16* Wt_uq  = (bf16*)(ws + off); off += (size_t)D_MODEL * PROJ * 2;
    bf16* Wt_ukv = (bf16*)(ws + off); off += (size_t)(2 * D_MODEL) * PROJ * 2;
    bf16* cq     = (bf16*)(ws + off); off += (size_t)TOK * PROJ * 2;
    bf16* ckv    = (bf16*)(ws + off); off += (size_t)TOK * PROJ * 2;
    bf16* Qh     = (bf16*)(ws + off); off += (size_t)TOK * D_MODEL * 2;
    bf16* Kh     = (bf16*)(ws + off); off += (size_t)TOK * D_MODEL * 2;
    bf16* Vt     = (bf16*)(ws + off); off += (size_t)TOK * D_MODEL * 2;
    bf16* AT     = (bf16*)(ws + off); off += (size_t)TOK * D_MODEL * 2;
    float* Opart = (float*)(ws + off); off += (size_t)8192 * 1024 * 4;   // 33.5 MB
    float* lpart = (float*)(ws + off); off += (size_t)8192 * 16 * 4;

    prep_weights_kernel<<<2048, 256, 0, stream>>>(
        W_o, W_dq, W_dkv, W_uq, W_ukv, Wo16, Wt_dq, Wt_dkv, Wt_uq, Wt_ukv);

    gemm_ln_kernel<<<dim3(TOK / 16, 2), 256, 0, stream>>>(
        x, Wt_dq, Wt_dkv, q_g, q_b, kv_g, kv_b, cq, ckv);

    gemm_lds_kernel<1, bf16><<<dim3(TOK / 64, D_MODEL / 128), 256, 0, stream>>>(
        cq, Wt_uq, Qh, nullptr, TOK, D_MODEL, PROJ);
    gemm_lds_kernel<2, bf16><<<dim3(TOK / 64, (2 * D_MODEL) / 128), 256, 0, stream>>>(
        ckv, Wt_ukv, Kh, Vt, TOK, 2 * D_MODEL, PROJ);

    attn_kernel<<<1024, 256, 0, stream>>>(Qh, Kh, Vt, Opart, lpart);
    combine_kernel<<<(32 * 2048 * 64) / 256, 256, 0, stream>>>(Opart, lpart, AT);

    gemm_lds_kernel<0, float><<<dim3(TOK / 64, D_MODEL / 128), 256, 0, stream>>>(
        AT, Wo16, (float*)d_out, nullptr, TOK, D_MODEL, D_MODEL);
}

// Round 13
// 266.048 us; speedup vs baseline: 1.0554x; 1.0554x over previous
//
#include <hip/hip_runtime.h>

typedef __bf16 bf16;
typedef __bf16 bf16x4 __attribute__((ext_vector_type(4)));
typedef __bf16 bf16x8 __attribute__((ext_vector_type(8)));
typedef float f32x4 __attribute__((ext_vector_type(4)));

#define D_MODEL 1024
#define PROJ    256
#define SEQ     2048
#define BATCH   2
#define TOK     4096   // BATCH*SEQ
#define NH      16
#define DH      64
#define NEG_BIG (-1e30f)
#define QSCALE  0.18033688011112042f   // 0.125 * log2(e), folded into Qh

#if __has_builtin(__builtin_amdgcn_exp2f)
#define EXP2(x) __builtin_amdgcn_exp2f(x)
#else
#define EXP2(x) exp2f(x)
#endif

typedef __attribute__((address_space(3))) unsigned int  lds_u32;
typedef __attribute__((address_space(1))) unsigned int  glb_u32;

// async 16B/lane global->LDS (gfx950 global_load_lds_dwordx4).
__device__ __forceinline__ void gl2lds16(const void* gsrc, void* ldst) {
    __builtin_amdgcn_global_load_lds((const glb_u32*)gsrc, (lds_u32*)ldst, 16, 0, 0);
}

// ---------------------------------------------------------------------------
// DPP 16-lane row sum (groups are contiguous 16-lane DPP rows).
template <int CTRL>
__device__ __forceinline__ float dppmov(float x) {
    int i = __builtin_bit_cast(int, x);
    i = __builtin_amdgcn_update_dpp(i, i, CTRL, 0xf, 0xf, false);
    return __builtin_bit_cast(float, i);
}
__device__ __forceinline__ float rowsum16(float v) {
    v += dppmov<0xB1>(v);
    v += dppmov<0x4E>(v);
    v += dppmov<0x141>(v);
    v += dppmov<0x140>(v);
    return v;
}

// ---------------------------------------------------------------------------
// One kernel for all weight prep: W_o cvt + 4 transposes (fp32 -> bf16 n-major).
__global__ void prep_weights_kernel(
    const float* __restrict__ W_o,  const float* __restrict__ W_dq,
    const float* __restrict__ W_dkv, const float* __restrict__ W_uq,
    const float* __restrict__ W_ukv,
    bf16* __restrict__ Wo16, bf16* __restrict__ Wt_dq, bf16* __restrict__ Wt_dkv,
    bf16* __restrict__ Wt_uq, bf16* __restrict__ Wt_ukv) {
    const int R0 = 1048576;
    const int R1 = R0 + 262144;
    const int R2 = R1 + 262144;
    const int R3 = R2 + 262144;
    const int R4 = R3 + 524288;
    for (int i = blockIdx.x * blockDim.x + threadIdx.x; i < R4;
         i += gridDim.x * blockDim.x) {
        if (i < R0) {
            Wo16[i] = (bf16)W_o[i];
        } else if (i < R1) {
            int j = i - R0, n = j >> 10, k = j & 1023;
            Wt_dq[j] = (bf16)W_dq[k * 256 + n];
        } else if (i < R2) {
            int j = i - R1, n = j >> 10, k = j & 1023;
            Wt_dkv[j] = (bf16)W_dkv[k * 256 + n];
        } else if (i < R3) {
            int j = i - R2, n = j >> 8, k = j & 255;
            Wt_uq[j] = (bf16)W_uq[k * 1024 + n];
        } else {
            int j = i - R3, n = j >> 8, k = j & 255;
            Wt_ukv[j] = (bf16)W_ukv[k * 2048 + n];
        }
    }
}

// ---------------------------------------------------------------------------
// Dual LN-GEMM: blockIdx.y=0 -> cq=LN(x@W_dq), =1 -> ckv=LN(x@W_dkv).
__global__ __launch_bounds__(256) void gemm_ln_kernel(
    const float* __restrict__ x,
    const bf16* __restrict__ Wt_q, const bf16* __restrict__ Wt_kv,
    const float* __restrict__ q_g, const float* __restrict__ q_b,
    const float* __restrict__ kv_g, const float* __restrict__ kv_b,
    bf16* __restrict__ cq, bf16* __restrict__ ckv) {
    const int K = 1024;
    const bf16* Wt = blockIdx.y ? Wt_kv : Wt_q;
    const float* gamma = blockIdx.y ? kv_g : q_g;
    const float* beta  = blockIdx.y ? kv_b : q_b;
    bf16* out = blockIdx.y ? ckv : cq;

    const int m0 = blockIdx.x * 16;
    const int wv = threadIdx.x >> 6;
    const int lane = threadIdx.x & 63;
    const int g = lane >> 4;
    const int ln16 = lane & 15;
    const int ncol0 = wv * 64;

    f32x4 acc[4] = {};
    const float* arow = x + (size_t)(m0 + ln16) * K + g * 8;
    for (int k0 = 0; k0 < K; k0 += 32) {
        f32x4 f0 = *(const f32x4*)(arow + k0);
        f32x4 f1 = *(const f32x4*)(arow + k0 + 4);
        bf16x8 a;
#pragma unroll
        for (int j = 0; j < 4; ++j) { a[j] = (bf16)f0[j]; a[4 + j] = (bf16)f1[j]; }
#pragma unroll
        for (int t = 0; t < 4; ++t) {
            const bf16* bp = Wt + (size_t)(ncol0 + 16 * t + ln16) * K + k0 + g * 8;
            bf16x8 b = *(const bf16x8*)bp;
            acc[t] = __builtin_amdgcn_mfma_f32_16x16x32_bf16(a, b, acc[t], 0, 0, 0);
        }
    }

    float s1[4], s2[4];
#pragma unroll
    for (int r = 0; r < 4; ++r) {
        float a = 0.f, b = 0.f;
#pragma unroll
        for (int t = 0; t < 4; ++t) { float v = acc[t][r]; a += v; b += v * v; }
        s1[r] = rowsum16(a); s2[r] = rowsum16(b);
    }
    __shared__ float red1[4][16];
    __shared__ float red2[4][16];
    if (ln16 == 0) {
#pragma unroll
        for (int r = 0; r < 4; ++r) {
            red1[wv][g * 4 + r] = s1[r];
            red2[wv][g * 4 + r] = s2[r];
        }
    }
    __syncthreads();
#pragma unroll
    for (int r = 0; r < 4; ++r) {
        int row = g * 4 + r;
        float t1 = red1[0][row] + red1[1][row] + red1[2][row] + red1[3][row];
        float t2 = red2[0][row] + red2[1][row] + red2[2][row] + red2[3][row];
        float mu = t1 * (1.0f / 256.0f);
        float var = t2 * (1.0f / 256.0f) - mu * mu;
        float rs = rsqrtf(var + 1e-5f);
#pragma unroll
        for (int t = 0; t < 4; ++t) {
            int col = ncol0 + 16 * t + ln16;
            float v = (acc[t][r] - mu) * rs * gamma[col] + beta[col];
            out[(size_t)(m0 + row) * PROJ + col] = (bf16)v;
        }
    }
}

// ---------------------------------------------------------------------------
// Shared m97-style LDS-staged GEMM body. BM=64, BN=128, BK=32, 4 waves/block.
// mode 0: C[M][N] row-major OutT; mode 1: Qh head-major (x QSCALE);
// mode 2: Kh head-major / Vt transposed.
template <typename OutT>
__device__ __forceinline__ void gemm_body(
    const bf16* __restrict__ A, const bf16* __restrict__ Bt,
    OutT* __restrict__ C, bf16* __restrict__ C2, int N, int K,
    int bx, int by, int mode, bf16* tA, bf16* tB) {
    const int w = threadIdx.x >> 6;
    const int lane = threadIdx.x & 63;
    const int g = lane >> 4;
    const int ln16 = lane & 15;
    const int wr = w >> 1;
    const int wc = w & 1;

    const int m0 = bx * 64;
    const int n0 = by * 128;

    const int crow = lane >> 2;
    const int ckc = lane & 3;
    const bf16* gA  = A  + (size_t)(m0 + w * 16 + crow) * K + ckc * 8;
    const bf16* gB0 = Bt + (size_t)(n0 + w * 16 + crow) * K + ckc * 8;
    const bf16* gB1 = Bt + (size_t)(n0 + 64 + w * 16 + crow) * K + ckc * 8;
    char* lA  = (char*)tA + w * 1024;
    char* lB0 = (char*)tB + w * 1024;
    char* lB1 = (char*)tB + 4096 + w * 1024;

    f32x4 acc[2][4] = {};
    for (int k0 = 0; k0 < K; k0 += 32) {
        gl2lds16(gA + k0, lA);
        gl2lds16(gB0 + k0, lB0);
        gl2lds16(gB1 + k0, lB1);
        __syncthreads();

        bf16x8 af[2], bf[4];
#pragma unroll
        for (int s = 0; s < 2; ++s)
            af[s] = *(const bf16x8*)(tA + (wr * 32 + s * 16 + ln16) * 32 + g * 8);
#pragma unroll
        for (int t = 0; t < 4; ++t)
            bf[t] = *(const bf16x8*)(tB + (wc * 64 + t * 16 + ln16) * 32 + g * 8);
#pragma unroll
        for (int s = 0; s < 2; ++s)
#pragma unroll
            for (int t = 0; t < 4; ++t)
                acc[s][t] = __builtin_amdgcn_mfma_f32_16x16x32_bf16(
                    af[s], bf[t], acc[s][t], 0, 0, 0);
        __syncthreads();
    }

#pragma unroll
    for (int s = 0; s < 2; ++s)
#pragma unroll
        for (int t = 0; t < 4; ++t) {
            const int col = n0 + wc * 64 + t * 16 + ln16;
            const int tok0 = m0 + wr * 32 + s * 16 + g * 4;
            if (mode == 2 && col >= 1024) {
                int cc = col - 1024;
                int h = cc >> 6, d = cc & 63;
                int b = tok0 >> 11, sq = tok0 & 2047;
                bf16x4 pk;
#pragma unroll
                for (int r = 0; r < 4; ++r) pk[r] = (bf16)acc[s][t][r];
                *(bf16x4*)(C2 + ((size_t)((b * 16 + h) * 64 + d) * SEQ + sq)) = pk;
            } else {
#pragma unroll
                for (int r = 0; r < 4; ++r) {
                    int row = tok0 + r;
                    float v = acc[s][t][r];
                    if (mode == 0) {
                        C[(size_t)row * N + col] = (OutT)v;
                    } else {
                        if (mode == 1) v *= QSCALE;
                        int h = col >> 6, d = col & 63;
                        int b = row >> 11, sq = row & 2047;
                        C[((size_t)((b * 16 + h) * 2048 + sq)) * 64 + d] = (OutT)v;
                    }
                }
            }
        }
}

// O-projection (mode 0, fp32 out)
__global__ __launch_bounds__(256) void gemm_o_kernel(
    const bf16* __restrict__ A, const bf16* __restrict__ Bt,
    float* __restrict__ C, int M, int N, int K) {
    __shared__ alignas(16) bf16 tA[64 * 32];
    __shared__ alignas(16) bf16 tB[128 * 32];
    gemm_body<float>(A, Bt, C, nullptr, N, K, blockIdx.x, blockIdx.y, 0, tA, tB);
}

// Merged Q-proj + KV-proj: blocks [0,512) = Q (64x8), [512,1536) = KV (64x16).
__global__ __launch_bounds__(256) void gemm_qkv_kernel(
    const bf16* __restrict__ cq, const bf16* __restrict__ Wt_uq,
    const bf16* __restrict__ ckv, const bf16* __restrict__ Wt_ukv,
    bf16* __restrict__ Qh, bf16* __restrict__ Kh, bf16* __restrict__ Vt) {
    __shared__ alignas(16) bf16 tA[64 * 32];
    __shared__ alignas(16) bf16 tB[128 * 32];
    const int i = blockIdx.x;
    if (i < 512) {
        gemm_body<bf16>(cq, Wt_uq, Qh, nullptr, D_MODEL, PROJ,
                        i >> 3, i & 7, 1, tA, tB);
    } else {
        const int j = i - 512;
        gemm_body<bf16>(ckv, Wt_ukv, Kh, Vt, 2 * D_MODEL, PROJ,
                        j >> 4, j & 15, 2, tA, tB);
    }
}

// ---------------------------------------------------------------------------
// Split-K paired flash attention, LDS-free k-loop (S^T = K·Q^T), with
// IN-BLOCK parity combine: both parity waves of a pair live in this block,
// so the epilogue merges them through LDS and writes final bf16 AT directly
// (no Opart/lpart scratch, no combine kernel).
__device__ __forceinline__ void load_kfrags(const bf16* __restrict__ Kbh, int k0,
                                            int g, int ln16, bf16x8* Kf) {
    const int base = ((ln16 & 12) << 1) + (ln16 & 3);   // 8*(ln16>>2)+(ln16&3)
#pragma unroll
    for (int c = 0; c < 4; ++c) {
        const int row = k0 + base + (c & 1) * 4 + ((c >> 1) << 5);
        const bf16* kp = Kbh + (size_t)row * DH + g * 8;
        Kf[2 * c]     = *(const bf16x8*)kp;
        Kf[2 * c + 1] = *(const bf16x8*)(kp + 32);
    }
}
__device__ __forceinline__ void load_vfrags(const bf16* __restrict__ Vbh, int k0,
                                            int g, int ln16, bf16x8* Vf) {
#pragma unroll
    for (int t = 0; t < 4; ++t) {
        const bf16* vp = Vbh + (size_t)(16 * t + ln16) * SEQ + k0 + g * 8;
        Vf[2 * t]     = *(const bf16x8*)vp;
        Vf[2 * t + 1] = *(const bf16x8*)(vp + 32);
    }
}

__device__ __forceinline__ void qk_exp_pack(
    int k0, int q, bool masked, int g, int ln16,
    bf16x8 aq0, bf16x8 aq1, const bf16x8* Kf,
    float& li, bf16x8& P1, bf16x8& P2) {
    f32x4 sc[4];
#pragma unroll
    for (int c = 0; c < 4; ++c) {
        f32x4 z = {};
        z = __builtin_amdgcn_mfma_f32_16x16x32_bf16(Kf[2 * c], aq0, z, 0, 0, 0);
        z = __builtin_amdgcn_mfma_f32_16x16x32_bf16(Kf[2 * c + 1], aq1, z, 0, 0, 0);
        sc[c] = z;
    }
    if (masked) {
        const int kb = k0 + 8 * g;
#pragma unroll
        for (int c = 0; c < 4; ++c)
#pragma unroll
            for (int r = 0; r < 4; ++r) {
                int kcol = kb + (c & 1) * 4 + r + ((c >> 1) << 5);
                if (kcol > q) sc[c][r] = NEG_BIG;
            }
    }
#pragma unroll
    for (int c = 0; c < 4; ++c)
#pragma unroll
        for (int r = 0; r < 4; ++r) {
            float p = EXP2(sc[c][r]);
            sc[c][r] = p;
            li += p;
        }
#pragma unroll
    for (int r = 0; r < 4; ++r) {
        P1[r] = (bf16)sc[0][r]; P1[4 + r] = (bf16)sc[1][r];
        P2[r] = (bf16)sc[2][r]; P2[4 + r] = (bf16)sc[3][r];
    }
}

__device__ __forceinline__ void pv_accum(
    bf16x8 P1, bf16x8 P2, const bf16x8* Vf, f32x4* o) {
#pragma unroll
    for (int t = 0; t < 4; ++t) {
        o[t] = __builtin_amdgcn_mfma_f32_16x16x32_bf16(Vf[2 * t], P1, o[t], 0, 0, 0);
        o[t] = __builtin_amdgcn_mfma_f32_16x16x32_bf16(Vf[2 * t + 1], P2, o[t], 0, 0, 0);
    }
}

__device__ __forceinline__ void do_tile(
    int kt, int lastL, int lastH, int qL, int qH, int g, int ln16,
    bf16x8 aqL0, bf16x8 aqL1, bf16x8 aqH0, bf16x8 aqH1,
    const bf16x8* Kf, const bf16x8* Vf,
    float& liL, float& liH, f32x4* oL, f32x4* oH) {
    const int k0 = kt * 64;
    const bool actL = (kt <= lastL);
    bf16x8 P1L, P2L, P1H, P2H;
    if (actL) qk_exp_pack(k0, qL, kt == lastL, g, ln16, aqL0, aqL1, Kf, liL, P1L, P2L);
    qk_exp_pack(k0, qH, kt == lastH, g, ln16, aqH0, aqH1, Kf, liH, P1H, P2H);
    if (actL) pv_accum(P1L, P2L, Vf, oL);
    pv_accum(P1H, P2H, Vf, oH);
}

// (256,2): (256,4) clamps to 64 VGPR and spills (round-7 evidence).
__global__ __launch_bounds__(256, 2) void attn_kernel(
    const bf16* __restrict__ Qh, const bf16* __restrict__ Kh,
    const bf16* __restrict__ Vt, bf16* __restrict__ AT) {
    // parity-exchange buffers: [pair][chain][q=16][d=64 pad to 68]
    __shared__ alignas(16) float xo[2][2][16][68];
    __shared__ float xl[2][2][16];

    const int lane = threadIdx.x & 63;
    const int g = lane >> 4;
    const int ln16 = lane & 15;
    const int wv = threadIdx.x >> 6;

    const int bh   = blockIdx.x & 31;
    const int gidx = blockIdx.x >> 5;          // 0..31
    const int pr   = wv >> 1;                  // pair slot in block
    const int p    = gidx * 2 + pr;            // 0..63
    const int sp   = wv & 1;                   // kt parity

    const int qbL = p * 16;
    const int qbH = (127 - p) * 16;
    const int lastL = p >> 2;
    const int lastH = (127 - p) >> 2;

    const bf16* Kbh = Kh + (size_t)bh * SEQ * DH;
    const bf16* Vbh = Vt + (size_t)bh * DH * SEQ;

    const bf16* qpL = Qh + ((size_t)bh * SEQ + qbL + ln16) * DH + g * 8;
    const bf16* qpH = Qh + ((size_t)bh * SEQ + qbH + ln16) * DH + g * 8;
    bf16x8 aqL0 = *(const bf16x8*)qpL, aqL1 = *(const bf16x8*)(qpL + 32);
    bf16x8 aqH0 = *(const bf16x8*)qpH, aqH1 = *(const bf16x8*)(qpH + 32);

    const int qL = qbL + ln16;
    const int qH = qbH + ln16;

    f32x4 oL[4] = {}, oH[4] = {};
    float liL = 0.f, liH = 0.f;

    bf16x8 Ka[8], Kb[8], Va[8], Vb[8];

    int kt = sp;
    for (; kt + 2 <= lastH; kt += 4) {
        load_kfrags(Kbh, kt * 64, g, ln16, Ka);
        load_vfrags(Vbh, kt * 64, g, ln16, Va);
        load_kfrags(Kbh, (kt + 2) * 64, g, ln16, Kb);
        load_vfrags(Vbh, (kt + 2) * 64, g, ln16, Vb);
        do_tile(kt, lastL, lastH, qL, qH, g, ln16,
                aqL0, aqL1, aqH0, aqH1, Ka, Va, liL, liH, oL, oH);
        do_tile(kt + 2, lastL, lastH, qL, qH, g, ln16,
                aqL0, aqL1, aqH0, aqH1, Kb, Vb, liL, liH, oL, oH);
    }
    if (kt <= lastH) {
        load_kfrags(Kbh, kt * 64, g, ln16, Ka);
        load_vfrags(Vbh, kt * 64, g, ln16, Va);
        do_tile(kt, lastL, lastH, qL, qH, g, ln16,
                aqL0, aqL1, aqH0, aqH1, Ka, Va, liL, liH, oL, oH);
    }

    // per-q sums (replicated across the 4 quads after butterfly)
    liL += __shfl_xor(liL, 16); liL += __shfl_xor(liL, 32);
    liH += __shfl_xor(liH, 16); liH += __shfl_xor(liH, 32);

    // parity sp=0 publishes partials; sp=1 merges, normalizes, writes AT.
    if (sp == 0) {
#pragma unroll
        for (int t = 0; t < 4; ++t) {
            *(f32x4*)&xo[pr][0][ln16][16 * t + 4 * g] = oL[t];
            *(f32x4*)&xo[pr][1][ln16][16 * t + 4 * g] = oH[t];
        }
        if (lane < 16) {
            xl[pr][0][ln16] = liL;
            xl[pr][1][ln16] = liH;
        }
    }
    __syncthreads();
    if (sp == 1) {
        const int b = bh >> 4, h = bh & 15;
        const size_t tokL = (size_t)(b * SEQ + qbL + ln16) * D_MODEL + h * DH;
        const size_t tokH = (size_t)(b * SEQ + qbH + ln16) * D_MODEL + h * DH;
        float invL = 1.0f / (liL + xl[pr][0][ln16]);
        float invH = 1.0f / (liH + xl[pr][1][ln16]);
#pragma unroll
        for (int t = 0; t < 4; ++t) {
            f32x4 aL = *(const f32x4*)&xo[pr][0][ln16][16 * t + 4 * g];
            f32x4 aH = *(const f32x4*)&xo[pr][1][ln16][16 * t + 4 * g];
            bf16x4 pkL, pkH;
#pragma unroll
            for (int r = 0; r < 4; ++r) {
                pkL[r] = (bf16)((oL[t][r] + aL[r]) * invL);
                pkH[r] = (bf16)((oH[t][r] + aH[r]) * invH);
            }
            *(bf16x4*)(AT + tokL + 16 * t + 4 * g) = pkL;
            *(bf16x4*)(AT + tokH + 16 * t + 4 * g) = pkH;
        }
    }
}

// ---------------------------------------------------------------------------
extern "C" void kernel_launch(void* const* d_in, const int* in_sizes, int n_in,
                              void* d_out, int out_size, void* d_ws, size_t ws_size,
                              hipStream_t stream) {
    const float* x     = (const float*)d_in[0];
    const float* W_dq  = (const float*)d_in[1];
    const float* W_uq  = (const float*)d_in[2];
    const float* q_g   = (const float*)d_in[3];
    const float* q_b   = (const float*)d_in[4];
    const float* W_dkv = (const float*)d_in[5];
    const float* W_ukv = (const float*)d_in[6];
    const float* kv_g  = (const float*)d_in[7];
    const float* kv_b  = (const float*)d_in[8];
    const float* W_o   = (const float*)d_in[9];

    char* ws = (char*)d_ws;
    size_t off = 0;
    bf16* Wo16   = (bf16*)(ws + off); off += (size_t)D_MODEL * D_MODEL * 2;
    bf16* Wt_dq  = (bf16*)(ws + off); off += (size_t)PROJ * D_MODEL * 2;
    bf16* Wt_dkv = (bf16*)(ws + off); off += (size_t)PROJ * D_MODEL * 2;
    bf16* Wt_uq  = (bf16*)(ws + off); off += (size_t)D_MODEL * PROJ * 2;
    bf16* Wt_ukv = (bf16*)(ws + off); off += (size_t)(2 * D_MODEL) * PROJ * 2;
    bf16* cq     = (bf16*)(ws + off); off += (size_t)TOK * PROJ * 2;
    bf16* ckv    = (bf16*)(ws + off); off += (size_t)TOK * PROJ * 2;
    bf16* Qh     = (bf16*)(ws + off); off += (size_t)TOK * D_MODEL * 2;
    bf16* Kh     = (bf16*)(ws + off); off += (size_t)TOK * D_MODEL * 2;
    bf16* Vt     = (bf16*)(ws + off); off += (size_t)TOK * D_MODEL * 2;
    bf16* AT     = (bf16*)(ws + off); off += (size_t)TOK * D_MODEL * 2;

    prep_weights_kernel<<<2048, 256, 0, stream>>>(
        W_o, W_dq, W_dkv, W_uq, W_ukv, Wo16, Wt_dq, Wt_dkv, Wt_uq, Wt_ukv);

    gemm_ln_kernel<<<dim3(TOK / 16, 2), 256, 0, stream>>>(
        x, Wt_dq, Wt_dkv, q_g, q_b, kv_g, kv_b, cq, ckv);

    // merged Q-proj + KV-proj
    gemm_qkv_kernel<<<1536, 256, 0, stream>>>(cq, Wt_uq, ckv, Wt_ukv, Qh, Kh, Vt);

    // attention with in-block parity combine -> AT directly
    attn_kernel<<<1024, 256, 0, stream>>>(Qh, Kh, Vt, AT);

    // out = attn @ W_o^T (fp32 out)
    gemm_o_kernel<<<dim3(TOK / 64, D_MODEL / 128), 256, 0, stream>>>(
        AT, Wo16, (float*)d_out, TOK, D_MODEL, D_MODEL);
}

// Round 14
// 218.725 us; speedup vs baseline: 1.2838x; 1.2164x over previous
//
#include <hip/hip_runtime.h>

typedef __bf16 bf16;
typedef __bf16 bf16x4 __attribute__((ext_vector_type(4)));
typedef __bf16 bf16x8 __attribute__((ext_vector_type(8)));
typedef float f32x4 __attribute__((ext_vector_type(4)));

#define D_MODEL 1024
#define PROJ    256
#define SEQ     2048
#define BATCH   2
#define TOK     4096   // BATCH*SEQ
#define NH      16
#define DH      64
#define NEG_BIG (-1e30f)
#define QSCALE  0.18033688011112042f   // 0.125 * log2(e), folded into Qh

#if __has_builtin(__builtin_amdgcn_exp2f)
#define EXP2(x) __builtin_amdgcn_exp2f(x)
#else
#define EXP2(x) exp2f(x)
#endif

typedef __attribute__((address_space(3))) unsigned int  lds_u32;
typedef __attribute__((address_space(1))) unsigned int  glb_u32;

// async 16B/lane global->LDS (gfx950 global_load_lds_dwordx4).
// LDS dest = wave-uniform base + lane*16 (m104/m108).
__device__ __forceinline__ void gl2lds16(const void* gsrc, void* ldst) {
    __builtin_amdgcn_global_load_lds((const glb_u32*)gsrc, (lds_u32*)ldst, 16, 0, 0);
}

// ---------------------------------------------------------------------------
// DPP 16-lane row sum (groups are contiguous 16-lane DPP rows).
template <int CTRL>
__device__ __forceinline__ float dppmov(float x) {
    int i = __builtin_bit_cast(int, x);
    i = __builtin_amdgcn_update_dpp(i, i, CTRL, 0xf, 0xf, false);
    return __builtin_bit_cast(float, i);
}
__device__ __forceinline__ float rowsum16(float v) {
    v += dppmov<0xB1>(v);
    v += dppmov<0x4E>(v);
    v += dppmov<0x141>(v);
    v += dppmov<0x140>(v);
    return v;
}

// ---------------------------------------------------------------------------
// One kernel for all weight prep: W_o cvt + 4 transposes (fp32 -> bf16 n-major).
__global__ void prep_weights_kernel(
    const float* __restrict__ W_o,  const float* __restrict__ W_dq,
    const float* __restrict__ W_dkv, const float* __restrict__ W_uq,
    const float* __restrict__ W_ukv,
    bf16* __restrict__ Wo16, bf16* __restrict__ Wt_dq, bf16* __restrict__ Wt_dkv,
    bf16* __restrict__ Wt_uq, bf16* __restrict__ Wt_ukv) {
    const int R0 = 1048576;
    const int R1 = R0 + 262144;
    const int R2 = R1 + 262144;
    const int R3 = R2 + 262144;
    const int R4 = R3 + 524288;
    for (int i = blockIdx.x * blockDim.x + threadIdx.x; i < R4;
         i += gridDim.x * blockDim.x) {
        if (i < R0) {
            Wo16[i] = (bf16)W_o[i];
        } else if (i < R1) {
            int j = i - R0, n = j >> 10, k = j & 1023;
            Wt_dq[j] = (bf16)W_dq[k * 256 + n];
        } else if (i < R2) {
            int j = i - R1, n = j >> 10, k = j & 1023;
            Wt_dkv[j] = (bf16)W_dkv[k * 256 + n];
        } else if (i < R3) {
            int j = i - R2, n = j >> 8, k = j & 255;
            Wt_uq[j] = (bf16)W_uq[k * 1024 + n];
        } else {
            int j = i - R3, n = j >> 8, k = j & 255;
            Wt_ukv[j] = (bf16)W_ukv[k * 2048 + n];
        }
    }
}

// ---------------------------------------------------------------------------
// Dual LN-GEMM: blockIdx.y=0 -> cq=LN(x@W_dq), =1 -> ckv=LN(x@W_dkv).
__global__ __launch_bounds__(256) void gemm_ln_kernel(
    const float* __restrict__ x,
    const bf16* __restrict__ Wt_q, const bf16* __restrict__ Wt_kv,
    const float* __restrict__ q_g, const float* __restrict__ q_b,
    const float* __restrict__ kv_g, const float* __restrict__ kv_b,
    bf16* __restrict__ cq, bf16* __restrict__ ckv) {
    const int K = 1024;
    const bf16* Wt = blockIdx.y ? Wt_kv : Wt_q;
    const float* gamma = blockIdx.y ? kv_g : q_g;
    const float* beta  = blockIdx.y ? kv_b : q_b;
    bf16* out = blockIdx.y ? ckv : cq;

    const int m0 = blockIdx.x * 16;
    const int wv = threadIdx.x >> 6;
    const int lane = threadIdx.x & 63;
    const int g = lane >> 4;
    const int ln16 = lane & 15;
    const int ncol0 = wv * 64;

    f32x4 acc[4] = {};
    const float* arow = x + (size_t)(m0 + ln16) * K + g * 8;
    for (int k0 = 0; k0 < K; k0 += 32) {
        f32x4 f0 = *(const f32x4*)(arow + k0);
        f32x4 f1 = *(const f32x4*)(arow + k0 + 4);
        bf16x8 a;
#pragma unroll
        for (int j = 0; j < 4; ++j) { a[j] = (bf16)f0[j]; a[4 + j] = (bf16)f1[j]; }
#pragma unroll
        for (int t = 0; t < 4; ++t) {
            const bf16* bp = Wt + (size_t)(ncol0 + 16 * t + ln16) * K + k0 + g * 8;
            bf16x8 b = *(const bf16x8*)bp;
            acc[t] = __builtin_amdgcn_mfma_f32_16x16x32_bf16(a, b, acc[t], 0, 0, 0);
        }
    }

    float s1[4], s2[4];
#pragma unroll
    for (int r = 0; r < 4; ++r) {
        float a = 0.f, b = 0.f;
#pragma unroll
        for (int t = 0; t < 4; ++t) { float v = acc[t][r]; a += v; b += v * v; }
        s1[r] = rowsum16(a); s2[r] = rowsum16(b);
    }
    __shared__ float red1[4][16];
    __shared__ float red2[4][16];
    if (ln16 == 0) {
#pragma unroll
        for (int r = 0; r < 4; ++r) {
            red1[wv][g * 4 + r] = s1[r];
            red2[wv][g * 4 + r] = s2[r];
        }
    }
    __syncthreads();
#pragma unroll
    for (int r = 0; r < 4; ++r) {
        int row = g * 4 + r;
        float t1 = red1[0][row] + red1[1][row] + red1[2][row] + red1[3][row];
        float t2 = red2[0][row] + red2[1][row] + red2[2][row] + red2[3][row];
        float mu = t1 * (1.0f / 256.0f);
        float var = t2 * (1.0f / 256.0f) - mu * mu;
        float rs = rsqrtf(var + 1e-5f);
#pragma unroll
        for (int t = 0; t < 4; ++t) {
            int col = ncol0 + 16 * t + ln16;
            float v = (acc[t][r] - mu) * rs * gamma[col] + beta[col];
            out[(size_t)(m0 + row) * PROJ + col] = (bf16)v;
        }
    }
}

// ---------------------------------------------------------------------------
// Shared m97-style LDS-staged GEMM body. BM=64, BN=128, BK=32, 4 waves/block.
template <typename OutT>
__device__ __forceinline__ void gemm_body(
    const bf16* __restrict__ A, const bf16* __restrict__ Bt,
    OutT* __restrict__ C, bf16* __restrict__ C2, int N, int K,
    int bx, int by, int mode, bf16* tA, bf16* tB) {
    const int w = threadIdx.x >> 6;
    const int lane = threadIdx.x & 63;
    const int g = lane >> 4;
    const int ln16 = lane & 15;
    const int wr = w >> 1;
    const int wc = w & 1;

    const int m0 = bx * 64;
    const int n0 = by * 128;

    const int crow = lane >> 2;
    const int ckc = lane & 3;
    const bf16* gA  = A  + (size_t)(m0 + w * 16 + crow) * K + ckc * 8;
    const bf16* gB0 = Bt + (size_t)(n0 + w * 16 + crow) * K + ckc * 8;
    const bf16* gB1 = Bt + (size_t)(n0 + 64 + w * 16 + crow) * K + ckc * 8;
    char* lA  = (char*)tA + w * 1024;
    char* lB0 = (char*)tB + w * 1024;
    char* lB1 = (char*)tB + 4096 + w * 1024;

    f32x4 acc[2][4] = {};
    for (int k0 = 0; k0 < K; k0 += 32) {
        gl2lds16(gA + k0, lA);
        gl2lds16(gB0 + k0, lB0);
        gl2lds16(gB1 + k0, lB1);
        __syncthreads();

        bf16x8 af[2], bf[4];
#pragma unroll
        for (int s = 0; s < 2; ++s)
            af[s] = *(const bf16x8*)(tA + (wr * 32 + s * 16 + ln16) * 32 + g * 8);
#pragma unroll
        for (int t = 0; t < 4; ++t)
            bf[t] = *(const bf16x8*)(tB + (wc * 64 + t * 16 + ln16) * 32 + g * 8);
#pragma unroll
        for (int s = 0; s < 2; ++s)
#pragma unroll
            for (int t = 0; t < 4; ++t)
                acc[s][t] = __builtin_amdgcn_mfma_f32_16x16x32_bf16(
                    af[s], bf[t], acc[s][t], 0, 0, 0);
        __syncthreads();
    }

#pragma unroll
    for (int s = 0; s < 2; ++s)
#pragma unroll
        for (int t = 0; t < 4; ++t) {
            const int col = n0 + wc * 64 + t * 16 + ln16;
            const int tok0 = m0 + wr * 32 + s * 16 + g * 4;
            if (mode == 2 && col >= 1024) {
                int cc = col - 1024;
                int h = cc >> 6, d = cc & 63;
                int b = tok0 >> 11, sq = tok0 & 2047;
                bf16x4 pk;
#pragma unroll
                for (int r = 0; r < 4; ++r) pk[r] = (bf16)acc[s][t][r];
                *(bf16x4*)(C2 + ((size_t)((b * 16 + h) * 64 + d) * SEQ + sq)) = pk;
            } else {
#pragma unroll
                for (int r = 0; r < 4; ++r) {
                    int row = tok0 + r;
                    float v = acc[s][t][r];
                    if (mode == 0) {
                        C[(size_t)row * N + col] = (OutT)v;
                    } else {
                        if (mode == 1) v *= QSCALE;
                        int h = col >> 6, d = col & 63;
                        int b = row >> 11, sq = row & 2047;
                        C[((size_t)((b * 16 + h) * 2048 + sq)) * 64 + d] = (OutT)v;
                    }
                }
            }
        }
}

// O-projection (mode 0, fp32 out)
__global__ __launch_bounds__(256) void gemm_o_kernel(
    const bf16* __restrict__ A, const bf16* __restrict__ Bt,
    float* __restrict__ C, int M, int N, int K) {
    __shared__ alignas(16) bf16 tA[64 * 32];
    __shared__ alignas(16) bf16 tB[128 * 32];
    gemm_body<float>(A, Bt, C, nullptr, N, K, blockIdx.x, blockIdx.y, 0, tA, tB);
}

// Merged Q-proj + KV-proj: blocks [0,512) = Q (64x8), [512,1536) = KV (64x16).
__global__ __launch_bounds__(256) void gemm_qkv_kernel(
    const bf16* __restrict__ cq, const bf16* __restrict__ Wt_uq,
    const bf16* __restrict__ ckv, const bf16* __restrict__ Wt_ukv,
    bf16* __restrict__ Qh, bf16* __restrict__ Kh, bf16* __restrict__ Vt) {
    __shared__ alignas(16) bf16 tA[64 * 32];
    __shared__ alignas(16) bf16 tB[128 * 32];
    const int i = blockIdx.x;
    if (i < 512) {
        gemm_body<bf16>(cq, Wt_uq, Qh, nullptr, D_MODEL, PROJ,
                        i >> 3, i & 7, 1, tA, tB);
    } else {
        const int j = i - 512;
        gemm_body<bf16>(ckv, Wt_ukv, Kh, Vt, 2 * D_MODEL, PROJ,
                        j >> 4, j & 15, 2, tA, tB);
    }
}

// ---------------------------------------------------------------------------
// Flash attention with COALESCED K/V staging through LDS.
// Block = (bh, 64-row q-supertile); 4 waves each own 16 q-rows and share the
// k-walk. Per k-tile: 16 block-wide global_load_lds_dwordx4 stage K (8KB
// contiguous) and V (128B row-chunks) into LDS; each wave ds_reads its MFMA
// fragments; S^T=K·Q^T -> exp -> P (registers) -> O^T += V^T·P^T.
__device__ __forceinline__ void qk_exp_pack(
    int k0, int q, bool masked, int g, int ln16,
    bf16x8 aq0, bf16x8 aq1, const bf16x8* Kf,
    float& li, bf16x8& P1, bf16x8& P2) {
    f32x4 sc[4];
#pragma unroll
    for (int c = 0; c < 4; ++c) {
        f32x4 z = {};
        z = __builtin_amdgcn_mfma_f32_16x16x32_bf16(Kf[2 * c], aq0, z, 0, 0, 0);
        z = __builtin_amdgcn_mfma_f32_16x16x32_bf16(Kf[2 * c + 1], aq1, z, 0, 0, 0);
        sc[c] = z;
    }
    if (masked) {
        const int kb = k0 + 8 * g;
#pragma unroll
        for (int c = 0; c < 4; ++c)
#pragma unroll
            for (int r = 0; r < 4; ++r) {
                int kcol = kb + (c & 1) * 4 + r + ((c >> 1) << 5);
                if (kcol > q) sc[c][r] = NEG_BIG;
            }
    }
#pragma unroll
    for (int c = 0; c < 4; ++c)
#pragma unroll
        for (int r = 0; r < 4; ++r) {
            float p = EXP2(sc[c][r]);
            sc[c][r] = p;
            li += p;
        }
#pragma unroll
    for (int r = 0; r < 4; ++r) {
        P1[r] = (bf16)sc[0][r]; P1[4 + r] = (bf16)sc[1][r];
        P2[r] = (bf16)sc[2][r]; P2[4 + r] = (bf16)sc[3][r];
    }
}

__device__ __forceinline__ void pv_accum(
    bf16x8 P1, bf16x8 P2, const bf16x8* Vf, f32x4* o) {
#pragma unroll
    for (int t = 0; t < 4; ++t) {
        o[t] = __builtin_amdgcn_mfma_f32_16x16x32_bf16(Vf[2 * t], P1, o[t], 0, 0, 0);
        o[t] = __builtin_amdgcn_mfma_f32_16x16x32_bf16(Vf[2 * t + 1], P2, o[t], 0, 0, 0);
    }
}

__global__ __launch_bounds__(256, 2) void attn_kernel(
    const bf16* __restrict__ Qh, const bf16* __restrict__ Kh,
    const bf16* __restrict__ Vt, bf16* __restrict__ AT) {
    __shared__ alignas(16) bf16 kbuf[64 * 64];   // [k][d], exact global copy
    __shared__ alignas(16) bf16 vbuf[64 * 64];   // [d][k]

    const int lane = threadIdx.x & 63;
    const int g = lane >> 4;
    const int ln16 = lane & 15;
    const int wv = threadIdx.x >> 6;

    const int bh = blockIdx.x & 31;
    const int qsuper = 31 - (blockIdx.x >> 5);   // heavy-first
    const int q0 = qsuper * 64;
    const int qb = q0 + wv * 16;                 // this wave's 16 q-rows
    const int q = qb + ln16;                     // this lane's q-row
    const int ntiles = qsuper + 1;

    const bf16* Kbh = Kh + (size_t)bh * SEQ * DH;
    const bf16* Vbh = Vt + (size_t)bh * DH * SEQ;

    const bf16* qp = Qh + ((size_t)bh * SEQ + qb + ln16) * DH + g * 8;
    bf16x8 aq0 = *(const bf16x8*)qp, aq1 = *(const bf16x8*)(qp + 32);

    f32x4 o[4] = {};
    float li = 0.f;

    // wave-uniform LDS staging bases (+ lane*16 implicit in HW)
    char* kd0 = (char*)kbuf + wv * 2048;
    char* kd1 = kd0 + 1024;
    char* vd0 = (char*)vbuf + wv * 2048;
    char* vd1 = vd0 + 1024;
    // per-lane global staging offsets
    const int kofs = wv * 1024 + lane * 8;                 // elements into K tile
    const size_t vrow0 = (size_t)(wv * 16 + (lane >> 3)) * SEQ;
    const size_t vrow1 = (size_t)(wv * 16 + 8 + (lane >> 3)) * SEQ;
    const int vcol = (lane & 7) * 8;

    const int row_base = ((ln16 & 12) << 1) + (ln16 & 3);  // 8*(ln16>>2)+(ln16&3)

    for (int kt = 0; kt < ntiles; ++kt) {
        const int k0 = kt * 64;
        gl2lds16(Kbh + (size_t)k0 * 64 + kofs, kd0);
        gl2lds16(Kbh + (size_t)k0 * 64 + kofs + 512, kd1);
        gl2lds16(Vbh + vrow0 + k0 + vcol, vd0);
        gl2lds16(Vbh + vrow1 + k0 + vcol, vd1);
        __syncthreads();   // drains vmcnt: tiles staged

        bf16x8 Kf[8], Vf[8];
#pragma unroll
        for (int c = 0; c < 4; ++c) {
            const int row = row_base + (c & 1) * 4 + ((c >> 1) << 5);
            Kf[2 * c]     = *(const bf16x8*)(kbuf + row * 64 + g * 8);
            Kf[2 * c + 1] = *(const bf16x8*)(kbuf + row * 64 + g * 8 + 32);
        }
#pragma unroll
        for (int t = 0; t < 4; ++t) {
            const int d = 16 * t + ln16;
            Vf[2 * t]     = *(const bf16x8*)(vbuf + d * 64 + g * 8);
            Vf[2 * t + 1] = *(const bf16x8*)(vbuf + d * 64 + g * 8 + 32);
        }

        bf16x8 P1, P2;
        qk_exp_pack(k0, q, kt == qsuper, g, ln16, aq0, aq1, Kf, li, P1, P2);
        pv_accum(P1, P2, Vf, o);
        __syncthreads();   // reads done before next tile overwrites
    }

    // per-q row sum: lanes sharing ln16 (across quads)
    li += __shfl_xor(li, 16); li += __shfl_xor(li, 32);
    float inv = 1.0f / li;

    const int b = bh >> 4, h = bh & 15;
    const size_t tok = (size_t)(b * SEQ + q) * D_MODEL + h * DH;
#pragma unroll
    for (int t = 0; t < 4; ++t) {
        bf16x4 pk;
#pragma unroll
        for (int r = 0; r < 4; ++r) pk[r] = (bf16)(o[t][r] * inv);
        *(bf16x4*)(AT + tok + 16 * t + 4 * g) = pk;
    }
}

// ---------------------------------------------------------------------------
extern "C" void kernel_launch(void* const* d_in, const int* in_sizes, int n_in,
                              void* d_out, int out_size, void* d_ws, size_t ws_size,
                              hipStream_t stream) {
    const float* x     = (const float*)d_in[0];
    const float* W_dq  = (const float*)d_in[1];
    const float* W_uq  = (const float*)d_in[2];
    const float* q_g   = (const float*)d_in[3];
    const float* q_b   = (const float*)d_in[4];
    const float* W_dkv = (const float*)d_in[5];
    const float* W_ukv = (const float*)d_in[6];
    const float* kv_g  = (const float*)d_in[7];
    const float* kv_b  = (const float*)d_in[8];
    const float* W_o   = (const float*)d_in[9];

    char* ws = (char*)d_ws;
    size_t off = 0;
    bf16* Wo16   = (bf16*)(ws + off); off += (size_t)D_MODEL * D_MODEL * 2;
    bf16* Wt_dq  = (bf16*)(ws + off); off += (size_t)PROJ * D_MODEL * 2;
    bf16* Wt_dkv = (bf16*)(ws + off); off += (size_t)PROJ * D_MODEL * 2;
    bf16* Wt_uq  = (bf16*)(ws + off); off += (size_t)D_MODEL * PROJ * 2;
    bf16* Wt_ukv = (bf16*)(ws + off); off += (size_t)(2 * D_MODEL) * PROJ * 2;
    bf16* cq     = (bf16*)(ws + off); off += (size_t)TOK * PROJ * 2;
    bf16* ckv    = (bf16*)(ws + off); off += (size_t)TOK * PROJ * 2;
    bf16* Qh     = (bf16*)(ws + off); off += (size_t)TOK * D_MODEL * 2;
    bf16* Kh     = (bf16*)(ws + off); off += (size_t)TOK * D_MODEL * 2;
    bf16* Vt     = (bf16*)(ws + off); off += (size_t)TOK * D_MODEL * 2;
    bf16* AT     = (bf16*)(ws + off); off += (size_t)TOK * D_MODEL * 2;

    prep_weights_kernel<<<2048, 256, 0, stream>>>(
        W_o, W_dq, W_dkv, W_uq, W_ukv, Wo16, Wt_dq, Wt_dkv, Wt_uq, Wt_ukv);

    gemm_ln_kernel<<<dim3(TOK / 16, 2), 256, 0, stream>>>(
        x, Wt_dq, Wt_dkv, q_g, q_b, kv_g, kv_b, cq, ckv);

    gemm_qkv_kernel<<<1536, 256, 0, stream>>>(cq, Wt_uq, ckv, Wt_ukv, Qh, Kh, Vt);

    attn_kernel<<<1024, 256, 0, stream>>>(Qh, Kh, Vt, AT);

    gemm_o_kernel<<<dim3(TOK / 64, D_MODEL / 128), 256, 0, stream>>>(
        AT, Wo16, (float*)d_out, TOK, D_MODEL, D_MODEL);
}

// Round 15
// 193.611 us; speedup vs baseline: 1.4503x; 1.1297x over previous
//
#include <hip/hip_runtime.h>

typedef __bf16 bf16;
typedef __bf16 bf16x4 __attribute__((ext_vector_type(4)));
typedef __bf16 bf16x8 __attribute__((ext_vector_type(8)));
typedef float f32x4 __attribute__((ext_vector_type(4)));

#define D_MODEL 1024
#define PROJ    256
#define SEQ     2048
#define BATCH   2
#define TOK     4096   // BATCH*SEQ
#define NH      16
#define DH      64
#define NEG_BIG (-1e30f)
#define QSCALE  0.18033688011112042f   // 0.125 * log2(e), folded into Qh

#if __has_builtin(__builtin_amdgcn_exp2f)
#define EXP2(x) __builtin_amdgcn_exp2f(x)
#else
#define EXP2(x) exp2f(x)
#endif

typedef __attribute__((address_space(3))) unsigned int  lds_u32;
typedef __attribute__((address_space(1))) unsigned int  glb_u32;

// async 16B/lane global->LDS (gfx950 global_load_lds_dwordx4).
// LDS dest = wave-uniform base + lane*16 (m104/m108).
__device__ __forceinline__ void gl2lds16(const void* gsrc, void* ldst) {
    __builtin_amdgcn_global_load_lds((const glb_u32*)gsrc, (lds_u32*)ldst, 16, 0, 0);
}

// ---------------------------------------------------------------------------
// DPP 16-lane row sum (groups are contiguous 16-lane DPP rows).
template <int CTRL>
__device__ __forceinline__ float dppmov(float x) {
    int i = __builtin_bit_cast(int, x);
    i = __builtin_amdgcn_update_dpp(i, i, CTRL, 0xf, 0xf, false);
    return __builtin_bit_cast(float, i);
}
__device__ __forceinline__ float rowsum16(float v) {
    v += dppmov<0xB1>(v);
    v += dppmov<0x4E>(v);
    v += dppmov<0x141>(v);
    v += dppmov<0x140>(v);
    return v;
}

// ---------------------------------------------------------------------------
// Weight prep + x fp32->bf16 conversion (all coalesced).
__global__ void prep_weights_kernel(
    const float* __restrict__ W_o,  const float* __restrict__ W_dq,
    const float* __restrict__ W_dkv, const float* __restrict__ W_uq,
    const float* __restrict__ W_ukv, const float* __restrict__ x,
    bf16* __restrict__ Wo16, bf16* __restrict__ Wt_dq, bf16* __restrict__ Wt_dkv,
    bf16* __restrict__ Wt_uq, bf16* __restrict__ Wt_ukv, bf16* __restrict__ x16) {
    const int R0 = 1048576;
    const int R1 = R0 + 262144;
    const int R2 = R1 + 262144;
    const int R3 = R2 + 262144;
    const int R4 = R3 + 524288;
    const int R5 = R4 + 4194304;     // x: 4096*1024
    for (int i = blockIdx.x * blockDim.x + threadIdx.x; i < R5;
         i += gridDim.x * blockDim.x) {
        if (i < R0) {
            Wo16[i] = (bf16)W_o[i];
        } else if (i < R1) {
            int j = i - R0, n = j >> 10, k = j & 1023;
            Wt_dq[j] = (bf16)W_dq[k * 256 + n];
        } else if (i < R2) {
            int j = i - R1, n = j >> 10, k = j & 1023;
            Wt_dkv[j] = (bf16)W_dkv[k * 256 + n];
        } else if (i < R3) {
            int j = i - R2, n = j >> 8, k = j & 255;
            Wt_uq[j] = (bf16)W_uq[k * 1024 + n];
        } else if (i < R4) {
            int j = i - R3, n = j >> 8, k = j & 255;
            Wt_ukv[j] = (bf16)W_ukv[k * 2048 + n];
        } else {
            int j = i - R4;
            x16[j] = (bf16)x[j];
        }
    }
}

// ---------------------------------------------------------------------------
// LDS-staged dual LN-GEMM. BM=32, full N=256 per block, BK=32.
// blockIdx.y=0 -> cq=LN(x@W_dq), =1 -> ckv=LN(x@W_dkv).
// 4 waves: wr=wv>>1 row-tile (16 rows), wc=wv&1 col-half (128 cols).
__global__ __launch_bounds__(256) void gemm_ln_kernel(
    const bf16* __restrict__ x16,
    const bf16* __restrict__ Wt_q, const bf16* __restrict__ Wt_kv,
    const float* __restrict__ q_g, const float* __restrict__ q_b,
    const float* __restrict__ kv_g, const float* __restrict__ kv_b,
    bf16* __restrict__ cq, bf16* __restrict__ ckv) {
    __shared__ alignas(16) bf16 xA[32 * 32];     // 2 KB
    __shared__ alignas(16) bf16 wB[256 * 32];    // 16 KB
    __shared__ float red1[4][16];
    __shared__ float red2[4][16];

    const int K = 1024;
    const bf16* Wt = blockIdx.y ? Wt_kv : Wt_q;
    const float* gamma = blockIdx.y ? kv_g : q_g;
    const float* beta  = blockIdx.y ? kv_b : q_b;
    bf16* out = blockIdx.y ? ckv : cq;

    const int m0 = blockIdx.x * 32;
    const int wv = threadIdx.x >> 6;
    const int lane = threadIdx.x & 63;
    const int g = lane >> 4;
    const int ln16 = lane & 15;
    const int wr = wv >> 1;
    const int wc = wv & 1;

    const int crow = lane >> 2;      // 0..15
    const int ckc = lane & 3;        // 16B chunk in a 64B (32-elem) k-row
    // xA staging: waves 0,1 stage rows m0+16wv..+15
    const bf16* gx = x16 + (size_t)(m0 + (wv & 1) * 16 + crow) * K + ckc * 8;
    char* lx = (char*)xA + (wv & 1) * 1024;
    // wB staging: wave wv stages n rows 64wv..64wv+63 (4 instrs of 16 rows)
    const bf16* gw = Wt + (size_t)(64 * wv + crow) * K + ckc * 8;
    char* lw = (char*)wB + wv * 4096;

    f32x4 acc[8] = {};
    for (int k0 = 0; k0 < K; k0 += 32) {
        if (wv < 2) gl2lds16(gx + k0, lx);
#pragma unroll
        for (int i = 0; i < 4; ++i)
            gl2lds16(gw + (size_t)i * 16 * K + k0, lw + i * 1024);
        __syncthreads();

        bf16x8 a = *(const bf16x8*)(xA + (wr * 16 + ln16) * 32 + g * 8);
#pragma unroll
        for (int t = 0; t < 8; ++t) {
            bf16x8 b = *(const bf16x8*)(wB + (wc * 128 + 16 * t + ln16) * 32 + g * 8);
            acc[t] = __builtin_amdgcn_mfma_f32_16x16x32_bf16(a, b, acc[t], 0, 0, 0);
        }
        __syncthreads();
    }

    // lane holds C rows m0+16wr+4g+r, cols 128wc+16t+ln16
    float s1[4], s2[4];
#pragma unroll
    for (int r = 0; r < 4; ++r) {
        float a = 0.f, b = 0.f;
#pragma unroll
        for (int t = 0; t < 8; ++t) { float v = acc[t][r]; a += v; b += v * v; }
        s1[r] = rowsum16(a); s2[r] = rowsum16(b);
    }
    if (ln16 == 0) {
#pragma unroll
        for (int r = 0; r < 4; ++r) {
            red1[wv][g * 4 + r] = s1[r];
            red2[wv][g * 4 + r] = s2[r];
        }
    }
    __syncthreads();
#pragma unroll
    for (int r = 0; r < 4; ++r) {
        int rl = g * 4 + r;
        float t1 = red1[wr * 2][rl] + red1[wr * 2 + 1][rl];
        float t2 = red2[wr * 2][rl] + red2[wr * 2 + 1][rl];
        float mu = t1 * (1.0f / 256.0f);
        float var = t2 * (1.0f / 256.0f) - mu * mu;
        float rs = rsqrtf(var + 1e-5f);
        int row = m0 + wr * 16 + rl;
#pragma unroll
        for (int t = 0; t < 8; ++t) {
            int col = wc * 128 + 16 * t + ln16;
            float v = (acc[t][r] - mu) * rs * gamma[col] + beta[col];
            out[(size_t)row * PROJ + col] = (bf16)v;
        }
    }
}

// ---------------------------------------------------------------------------
// Shared m97-style LDS-staged GEMM body. BM=64, BN=128, BK=32, 4 waves/block.
template <typename OutT>
__device__ __forceinline__ void gemm_body(
    const bf16* __restrict__ A, const bf16* __restrict__ Bt,
    OutT* __restrict__ C, bf16* __restrict__ C2, int N, int K,
    int bx, int by, int mode, bf16* tA, bf16* tB) {
    const int w = threadIdx.x >> 6;
    const int lane = threadIdx.x & 63;
    const int g = lane >> 4;
    const int ln16 = lane & 15;
    const int wr = w >> 1;
    const int wc = w & 1;

    const int m0 = bx * 64;
    const int n0 = by * 128;

    const int crow = lane >> 2;
    const int ckc = lane & 3;
    const bf16* gA  = A  + (size_t)(m0 + w * 16 + crow) * K + ckc * 8;
    const bf16* gB0 = Bt + (size_t)(n0 + w * 16 + crow) * K + ckc * 8;
    const bf16* gB1 = Bt + (size_t)(n0 + 64 + w * 16 + crow) * K + ckc * 8;
    char* lA  = (char*)tA + w * 1024;
    char* lB0 = (char*)tB + w * 1024;
    char* lB1 = (char*)tB + 4096 + w * 1024;

    f32x4 acc[2][4] = {};
    for (int k0 = 0; k0 < K; k0 += 32) {
        gl2lds16(gA + k0, lA);
        gl2lds16(gB0 + k0, lB0);
        gl2lds16(gB1 + k0, lB1);
        __syncthreads();

        bf16x8 af[2], bf[4];
#pragma unroll
        for (int s = 0; s < 2; ++s)
            af[s] = *(const bf16x8*)(tA + (wr * 32 + s * 16 + ln16) * 32 + g * 8);
#pragma unroll
        for (int t = 0; t < 4; ++t)
            bf[t] = *(const bf16x8*)(tB + (wc * 64 + t * 16 + ln16) * 32 + g * 8);
#pragma unroll
        for (int s = 0; s < 2; ++s)
#pragma unroll
            for (int t = 0; t < 4; ++t)
                acc[s][t] = __builtin_amdgcn_mfma_f32_16x16x32_bf16(
                    af[s], bf[t], acc[s][t], 0, 0, 0);
        __syncthreads();
    }

#pragma unroll
    for (int s = 0; s < 2; ++s)
#pragma unroll
        for (int t = 0; t < 4; ++t) {
            const int col = n0 + wc * 64 + t * 16 + ln16;
            const int tok0 = m0 + wr * 32 + s * 16 + g * 4;
            if (mode == 2 && col >= 1024) {
                int cc = col - 1024;
                int h = cc >> 6, d = cc & 63;
                int b = tok0 >> 11, sq = tok0 & 2047;
                bf16x4 pk;
#pragma unroll
                for (int r = 0; r < 4; ++r) pk[r] = (bf16)acc[s][t][r];
                *(bf16x4*)(C2 + ((size_t)((b * 16 + h) * 64 + d) * SEQ + sq)) = pk;
            } else {
#pragma unroll
                for (int r = 0; r < 4; ++r) {
                    int row = tok0 + r;
                    float v = acc[s][t][r];
                    if (mode == 0) {
                        C[(size_t)row * N + col] = (OutT)v;
                    } else {
                        if (mode == 1) v *= QSCALE;
                        int h = col >> 6, d = col & 63;
                        int b = row >> 11, sq = row & 2047;
                        C[((size_t)((b * 16 + h) * 2048 + sq)) * 64 + d] = (OutT)v;
                    }
                }
            }
        }
}

// O-projection (mode 0, fp32 out)
__global__ __launch_bounds__(256) void gemm_o_kernel(
    const bf16* __restrict__ A, const bf16* __restrict__ Bt,
    float* __restrict__ C, int M, int N, int K) {
    __shared__ alignas(16) bf16 tA[64 * 32];
    __shared__ alignas(16) bf16 tB[128 * 32];
    gemm_body<float>(A, Bt, C, nullptr, N, K, blockIdx.x, blockIdx.y, 0, tA, tB);
}

// Merged Q-proj + KV-proj: blocks [0,512) = Q (64x8), [512,1536) = KV (64x16).
__global__ __launch_bounds__(256) void gemm_qkv_kernel(
    const bf16* __restrict__ cq, const bf16* __restrict__ Wt_uq,
    const bf16* __restrict__ ckv, const bf16* __restrict__ Wt_ukv,
    bf16* __restrict__ Qh, bf16* __restrict__ Kh, bf16* __restrict__ Vt) {
    __shared__ alignas(16) bf16 tA[64 * 32];
    __shared__ alignas(16) bf16 tB[128 * 32];
    const int i = blockIdx.x;
    if (i < 512) {
        gemm_body<bf16>(cq, Wt_uq, Qh, nullptr, D_MODEL, PROJ,
                        i >> 3, i & 7, 1, tA, tB);
    } else {
        const int j = i - 512;
        gemm_body<bf16>(ckv, Wt_ukv, Kh, Vt, 2 * D_MODEL, PROJ,
                        j >> 4, j & 15, 2, tA, tB);
    }
}

// ---------------------------------------------------------------------------
// Flash attention, coalesced LDS staging + XOR-swizzled layout.
// Rows are 128B = 8 slots of 16B. Chunk c of row r is stored at slot
// c ^ f(r), f(r) = (r&3)|(((r>>3)&1)<<2). Staging stays HW-contiguous
// (swizzle applied to the per-lane GLOBAL source address); fragment reads
// then land 2 lanes/bank-group -> 2-way conflicts = free (m136).
__device__ __forceinline__ void qk_exp_pack(
    int k0, int q, bool masked, int g, int ln16,
    bf16x8 aq0, bf16x8 aq1, const bf16x8* Kf,
    float& li, bf16x8& P1, bf16x8& P2) {
    f32x4 sc[4];
#pragma unroll
    for (int c = 0; c < 4; ++c) {
        f32x4 z = {};
        z = __builtin_amdgcn_mfma_f32_16x16x32_bf16(Kf[2 * c], aq0, z, 0, 0, 0);
        z = __builtin_amdgcn_mfma_f32_16x16x32_bf16(Kf[2 * c + 1], aq1, z, 0, 0, 0);
        sc[c] = z;
    }
    if (masked) {
        const int kb = k0 + 8 * g;
#pragma unroll
        for (int c = 0; c < 4; ++c)
#pragma unroll
            for (int r = 0; r < 4; ++r) {
                int kcol = kb + (c & 1) * 4 + r + ((c >> 1) << 5);
                if (kcol > q) sc[c][r] = NEG_BIG;
            }
    }
#pragma unroll
    for (int c = 0; c < 4; ++c)
#pragma unroll
        for (int r = 0; r < 4; ++r) {
            float p = EXP2(sc[c][r]);
            sc[c][r] = p;
            li += p;
        }
#pragma unroll
    for (int r = 0; r < 4; ++r) {
        P1[r] = (bf16)sc[0][r]; P1[4 + r] = (bf16)sc[1][r];
        P2[r] = (bf16)sc[2][r]; P2[4 + r] = (bf16)sc[3][r];
    }
}

__device__ __forceinline__ void pv_accum(
    bf16x8 P1, bf16x8 P2, const bf16x8* Vf, f32x4* o) {
#pragma unroll
    for (int t = 0; t < 4; ++t) {
        o[t] = __builtin_amdgcn_mfma_f32_16x16x32_bf16(Vf[2 * t], P1, o[t], 0, 0, 0);
        o[t] = __builtin_amdgcn_mfma_f32_16x16x32_bf16(Vf[2 * t + 1], P2, o[t], 0, 0, 0);
    }
}

__global__ __launch_bounds__(256, 2) void attn_kernel(
    const bf16* __restrict__ Qh, const bf16* __restrict__ Kh,
    const bf16* __restrict__ Vt, bf16* __restrict__ AT) {
    __shared__ alignas(16) bf16 kbuf[64 * 64];   // [k][d], swizzled slots
    __shared__ alignas(16) bf16 vbuf[64 * 64];   // [d][k], swizzled slots

    const int lane = threadIdx.x & 63;
    const int g = lane >> 4;
    const int ln16 = lane & 15;
    const int wv = threadIdx.x >> 6;

    const int bh = blockIdx.x & 31;
    const int qsuper = 31 - (blockIdx.x >> 5);   // heavy-first
    const int qb = qsuper * 64 + wv * 16;        // this wave's 16 q-rows
    const int q = qb + ln16;
    const int ntiles = qsuper + 1;

    const bf16* Kbh = Kh + (size_t)bh * SEQ * DH;
    const bf16* Vbh = Vt + (size_t)bh * DH * SEQ;

    const bf16* qp = Qh + ((size_t)bh * SEQ + q) * DH + g * 8;
    bf16x8 aq0 = *(const bf16x8*)qp, aq1 = *(const bf16x8*)(qp + 32);

    f32x4 o[4] = {};
    float li = 0.f;

    // wave-uniform LDS staging bases
    char* kd0 = (char*)kbuf + wv * 2048;
    char* kd1 = kd0 + 1024;
    char* vd0 = (char*)vbuf + wv * 2048;
    char* vd1 = vd0 + 1024;
    // per-lane swizzled global source offsets
    const int rho = lane >> 3;                 // row within 8-row staging group
    const int sl  = lane & 7;                  // dest slot
    const int c0 = sl ^ (rho & 3);             // f(r)=rho&3      (rows 16wv+rho)
    const int c1 = sl ^ ((rho & 3) | 4);       // f(r)=(rho&3)|4  (rows 16wv+8+rho)
    const int kofs0 = (16 * wv + rho) * 64 + c0 * 8;
    const int kofs1 = (16 * wv + 8 + rho) * 64 + c1 * 8;
    const size_t vrow0 = (size_t)(16 * wv + rho) * SEQ;
    const size_t vrow1 = (size_t)(16 * wv + 8 + rho) * SEQ;
    const int vc0 = c0 * 8, vc1 = c1 * 8;

    // loop-invariant swizzled fragment-read addresses
    const int row_base = ((ln16 & 12) << 1) + (ln16 & 3);  // 8*(ln16>>2)+(ln16&3)
    const bf16* kr[4];
#pragma unroll
    for (int c = 0; c < 4; ++c) {
        const int row = row_base + (c & 1) * 4 + ((c >> 1) << 5);
        const int fr = (row & 3) | (((row >> 3) & 1) << 2);
        kr[c] = kbuf + row * 64 + ((g ^ fr) * 8);
    }
    const bf16* vr[4];
#pragma unroll
    for (int t = 0; t < 4; ++t) {
        const int d = 16 * t + ln16;
        const int fd = (d & 3) | (((d >> 3) & 1) << 2);
        vr[t] = vbuf + d * 64 + ((g ^ fd) * 8);
    }

    for (int kt = 0; kt < ntiles; ++kt) {
        const int k0 = kt * 64;
        gl2lds16(Kbh + (size_t)k0 * 64 + kofs0, kd0);
        gl2lds16(Kbh + (size_t)k0 * 64 + kofs1, kd1);
        gl2lds16(Vbh + vrow0 + k0 + vc0, vd0);
        gl2lds16(Vbh + vrow1 + k0 + vc1, vd1);
        __syncthreads();   // drains vmcnt: tiles staged

        bf16x8 Kf[8], Vf[8];
#pragma unroll
        for (int c = 0; c < 4; ++c) {
            Kf[2 * c]     = *(const bf16x8*)(kr[c]);
            Kf[2 * c + 1] = *(const bf16x8*)((const bf16*)((size_t)kr[c] ^ 64));
        }
#pragma unroll
        for (int t = 0; t < 4; ++t) {
            Vf[2 * t]     = *(const bf16x8*)(vr[t]);
            Vf[2 * t + 1] = *(const bf16x8*)((const bf16*)((size_t)vr[t] ^ 64));
        }

        bf16x8 P1, P2;
        qk_exp_pack(k0, q, kt == qsuper, g, ln16, aq0, aq1, Kf, li, P1, P2);
        pv_accum(P1, P2, Vf, o);
        __syncthreads();   // reads done before next tile overwrites
    }

    li += __shfl_xor(li, 16); li += __shfl_xor(li, 32);
    float inv = 1.0f / li;

    const int b = bh >> 4, h = bh & 15;
    const size_t tok = (size_t)(b * SEQ + q) * D_MODEL + h * DH;
#pragma unroll
    for (int t = 0; t < 4; ++t) {
        bf16x4 pk;
#pragma unroll
        for (int r = 0; r < 4; ++r) pk[r] = (bf16)(o[t][r] * inv);
        *(bf16x4*)(AT + tok + 16 * t + 4 * g) = pk;
    }
}

// ---------------------------------------------------------------------------
extern "C" void kernel_launch(void* const* d_in, const int* in_sizes, int n_in,
                              void* d_out, int out_size, void* d_ws, size_t ws_size,
                              hipStream_t stream) {
    const float* x     = (const float*)d_in[0];
    const float* W_dq  = (const float*)d_in[1];
    const float* W_uq  = (const float*)d_in[2];
    const float* q_g   = (const float*)d_in[3];
    const float* q_b   = (const float*)d_in[4];
    const float* W_dkv = (const float*)d_in[5];
    const float* W_ukv = (const float*)d_in[6];
    const float* kv_g  = (const float*)d_in[7];
    const float* kv_b  = (const float*)d_in[8];
    const float* W_o   = (const float*)d_in[9];

    char* ws = (char*)d_ws;
    size_t off = 0;
    bf16* Wo16   = (bf16*)(ws + off); off += (size_t)D_MODEL * D_MODEL * 2;
    bf16* Wt_dq  = (bf16*)(ws + off); off += (size_t)PROJ * D_MODEL * 2;
    bf16* Wt_dkv = (bf16*)(ws + off); off += (size_t)PROJ * D_MODEL * 2;
    bf16* Wt_uq  = (bf16*)(ws + off); off += (size_t)D_MODEL * PROJ * 2;
    bf16* Wt_ukv = (bf16*)(ws + off); off += (size_t)(2 * D_MODEL) * PROJ * 2;
    bf16* x16    = (bf16*)(ws + off); off += (size_t)TOK * D_MODEL * 2;
    bf16* cq     = (bf16*)(ws + off); off += (size_t)TOK * PROJ * 2;
    bf16* ckv    = (bf16*)(ws + off); off += (size_t)TOK * PROJ * 2;
    bf16* Qh     = (bf16*)(ws + off); off += (size_t)TOK * D_MODEL * 2;
    bf16* Kh     = (bf16*)(ws + off); off += (size_t)TOK * D_MODEL * 2;
    bf16* Vt     = (bf16*)(ws + off); off += (size_t)TOK * D_MODEL * 2;
    bf16* AT     = (bf16*)(ws + off); off += (size_t)TOK * D_MODEL * 2;

    prep_weights_kernel<<<2048, 256, 0, stream>>>(
        W_o, W_dq, W_dkv, W_uq, W_ukv, x,
        Wo16, Wt_dq, Wt_dkv, Wt_uq, Wt_ukv, x16);

    gemm_ln_kernel<<<dim3(TOK / 32, 2), 256, 0, stream>>>(
        x16, Wt_dq, Wt_dkv, q_g, q_b, kv_g, kv_b, cq, ckv);

    gemm_qkv_kernel<<<1536, 256, 0, stream>>>(cq, Wt_uq, ckv, Wt_ukv, Qh, Kh, Vt);

    attn_kernel<<<1024, 256, 0, stream>>>(Qh, Kh, Vt, AT);

    gemm_o_kernel<<<dim3(TOK / 64, D_MODEL / 128), 256, 0, stream>>>(
        AT, Wo16, (float*)d_out, TOK, D_MODEL, D_MODEL);
}